// Round 3
// baseline (250.700 us; speedup 1.0000x reference)
//
#include <hip/hip_runtime.h>
#include <math.h>

// ws layout (float offsets) — tiny now: everything batch-sized lives in LDS.
#define WS_KV    0     // 300: Wk @ u
#define WS_C0    300   // bk . u
#define WS_C1    301   // bq . u2
#define WS_H0    304   // 300: Wq @ u2
#define WS_H1    604   // 300: g = Wx^3 (Wq u2)  (final, written by k_hops3)
#define WS_DUMMY 904   // 300: Wx L3-warm sink (never read)

__device__ __forceinline__ float wred(float v) {
#pragma unroll
    for (int off = 32; off > 0; off >>= 1) v += __shfl_xor(v, off);
    return v;
}

// ---------------------------------------------------------------------------
// k_prep: grid 302 x 64. One wave per output row.
//  blocks 0..299: kv[j] = dot(Wk row j, u); h0[j] = dot(Wq row j, u2);
//                 also stream Wx row j once (warms L3 for k_hops3).
//  block 300: c0 = bk.u ; block 301: c1 = bq.u2
// ---------------------------------------------------------------------------
__global__ __launch_bounds__(64) void k_prep(
    const float* __restrict__ Wk, const float* __restrict__ bk,
    const float* __restrict__ Wq, const float* __restrict__ bq,
    const float* __restrict__ Wx, const float* __restrict__ wmlp,
    float* __restrict__ ws)
{
    const int lane = threadIdx.x;
    const int j = blockIdx.x;
    const float* u  = wmlp;
    const float* u2 = wmlp + 300;
    if (j < 300) {
        float pk = 0.f, pq = 0.f, pw = 0.f;
#pragma unroll
        for (int k = 0; k < 5; ++k) {
            int idx = lane + 64 * k;
            if (idx < 300) {
                pk += Wk[j * 300 + idx] * u[idx];
                pq += Wq[j * 300 + idx] * u2[idx];
                pw += Wx[j * 300 + idx];           // L3 warm for k_hops3
            }
        }
        pk = wred(pk); pq = wred(pq); pw = wred(pw);
        if (lane == 0) {
            ws[WS_KV + j] = pk;
            ws[WS_H0 + j] = pq;
            ws[WS_DUMMY + j] = pw;   // keep the warm loads live (no DCE)
        }
    } else if (j == 300) {
        float p = 0.f;
#pragma unroll
        for (int k = 0; k < 5; ++k) { int idx = lane + 64 * k; if (idx < 300) p += bk[idx] * u[idx]; }
        p = wred(p);
        if (lane == 0) ws[WS_C0] = p;
    } else {
        float p = 0.f;
#pragma unroll
        for (int k = 0; k < 5; ++k) { int idx = lane + 64 * k; if (idx < 300) p += bq[idx] * u2[idx]; }
        p = wred(p);
        if (lane == 0) ws[WS_C1] = p;
    }
}

// ---------------------------------------------------------------------------
// k_hops3: grid 1 x 1024 (16 waves). Three chained GEMVs h <- Wx @ h entirely
// in LDS (ping-pong). Wave w handles rows {w, w+16, ...}; each row-dot is a
// coalesced 1200B load + shuffle reduce. Wx is L3-warm from k_prep.
// g = Wx^3 @ h0 lands in ws[WS_H1].
// ---------------------------------------------------------------------------
__global__ __launch_bounds__(1024) void k_hops3(
    const float* __restrict__ Wx, float* __restrict__ ws)
{
    const int t = threadIdx.x;
    const int wv = t >> 6;
    const int lane = t & 63;
    __shared__ float ha[300];
    __shared__ float hb[300];

    if (t < 300) ha[t] = ws[WS_H0 + t];
    __syncthreads();

    for (int hop = 0; hop < 3; ++hop) {
        const float* s_ = (hop & 1) ? hb : ha;
        float* d_ = (hop & 1) ? ha : hb;
        // ILP-2 row pairs: j and j+16
        for (int i = 0; i < 20; i += 2) {
            const int j0 = wv + 16 * i;
            const int j1 = j0 + 16;
            const int jj0 = (j0 < 300) ? j0 : 0;   // safe address, result masked
            const int jj1 = (j1 < 300) ? j1 : 0;
            float p0 = 0.f, p1 = 0.f;
#pragma unroll
            for (int k = 0; k < 5; ++k) {
                int idx = lane + 64 * k;
                if (idx < 300) {
                    float sv = s_[idx];
                    p0 += Wx[jj0 * 300 + idx] * sv;
                    p1 += Wx[jj1 * 300 + idx] * sv;
                }
            }
#pragma unroll
            for (int off = 32; off > 0; off >>= 1) {
                p0 += __shfl_xor(p0, off);
                p1 += __shfl_xor(p1, off);
            }
            if (lane == 0) {
                if (j0 < 300) d_[j0] = p0;
                if (j1 < 300) d_[j1] = p1;
            }
        }
        __syncthreads();
    }
    // after hops 0,1,2 the result is in hb
    if (t < 300) ws[WS_H1 + t] = hb[t];
}

// ---------------------------------------------------------------------------
// k_fused: grid 256 x 1024. One block per batch row.
// Phase A: counts + qb. Phase B: gather/attention (16 waves x 32 tokens,
// float4 row loads, ILP-2, fast exp(tanh)). Phase C: in-LDS combine.
// Phase D: tail GEMV chain (3-way K-split over 960 threads) + softmax out.
// No ws round-trip for mw/v_s — everything stays in LDS.
// ---------------------------------------------------------------------------
__global__ __launch_bounds__(1024) void k_fused(
    const int* __restrict__ text, const int* __restrict__ aspect,
    const int* __restrict__ left, const float* __restrict__ embed,
    const float* __restrict__ Wk, const float* __restrict__ bk,
    const float* __restrict__ Wproj, const float* __restrict__ bproj,
    const float* __restrict__ Wm, const float* __restrict__ bm,
    const float* __restrict__ Wd, const float* __restrict__ bd,
    float* __restrict__ out, const float* __restrict__ ws)
{
    const int b = blockIdx.x;
    const int t = threadIdx.x;
    const int wv = t >> 6;
    const int lane = t & 63;

    __shared__ int   toks[512];
    __shared__ int   atoks[8];
    __shared__ float red[16];
    __shared__ __align__(16) float accW[16 * 300];
    __shared__ __align__(16) float vsW[16 * 300];
    __shared__ float denomW[16];
    __shared__ int   cnts[3];
    __shared__ float sc[4];
    __shared__ float A[300], VS[300], T[300], part[900], vms[300], lg[3];

    if (t < 3) cnts[t] = 0;
    __syncthreads();

    bool predm = false, predl = false, preda = false;
    if (t < 512) { int tk = text[b * 512 + t]; toks[t] = tk; predm = (tk != 0); }
    else if (t < 576) predl = (left[b * 64 + (t - 512)] != 0);
    else if (t < 584) { int a = t - 576; int ak = aspect[b * 8 + a]; atoks[a] = ak; preda = (ak != 0); }
    {
        unsigned long long m;
        m = __ballot(predm); if (lane == 0 && m) atomicAdd(&cnts[0], __popcll(m));
        m = __ballot(predl); if (lane == 0 && m) atomicAdd(&cnts[1], __popcll(m));
        m = __ballot(preda); if (lane == 0 && m) atomicAdd(&cnts[2], __popcll(m));
    }
    __syncthreads();

    // qb = asp_e . g + bk.u + bq.u2   (wave-partial shuffle reduce)
    float prod = 0.f;
    if (t < 300) {
        float s = 0.f;
#pragma unroll
        for (int a = 0; a < 8; ++a) s += embed[(size_t)atoks[a] * 300 + t];
        prod = (s / (float)cnts[2]) * ws[WS_H1 + t];
    }
    prod = wred(prod);
    if (lane == 0) red[wv] = prod;
    __syncthreads();
    if (t == 0) {
        sc[0] = (float)cnts[0];
        sc[1] = (float)(cnts[1] - cnts[2]);
        sc[2] = (float)cnts[1];
        float q = 0.f;
#pragma unroll
        for (int w = 0; w < 16; ++w) q += red[w];
        sc[3] = q + ws[WS_C0] + ws[WS_C1];
    }
    __syncthreads();
    const float mem_len_f = sc[0], startf = sc[1], endf = sc[2], qb = sc[3];

    const float4* kv4 = (const float4*)(ws + WS_KV);
    const float4* emb4 = (const float4*)embed;   // row = tok*75 float4s
    const bool hasB = (lane < 11);
    const float4 kva = kv4[lane];
    const float4 kvb = hasB ? kv4[64 + lane] : make_float4(0.f, 0.f, 0.f, 0.f);

    float4 accA = make_float4(0.f,0.f,0.f,0.f), accB = make_float4(0.f,0.f,0.f,0.f);
    float4 vsA  = make_float4(0.f,0.f,0.f,0.f), vsB  = make_float4(0.f,0.f,0.f,0.f);
    float denom = 0.f;

    for (int it = 0; it < 16; ++it) {
        const int l0 = wv * 32 + 2 * it, l1 = l0 + 1;
        const long r0 = (long)toks[l0] * 75, r1 = (long)toks[l1] * 75;
        float4 a0 = emb4[r0 + lane];
        float4 a1 = emb4[r1 + lane];
        float4 b0 = hasB ? emb4[r0 + 64 + lane] : make_float4(0.f,0.f,0.f,0.f);
        float4 b1 = hasB ? emb4[r1 + 64 + lane] : make_float4(0.f,0.f,0.f,0.f);

        float pd0 = a0.x*kva.x + a0.y*kva.y + a0.z*kva.z + a0.w*kva.w
                  + b0.x*kvb.x + b0.y*kvb.y + b0.z*kvb.z + b0.w*kvb.w;
        float pd1 = a1.x*kva.x + a1.y*kva.y + a1.z*kva.z + a1.w*kva.w
                  + b1.x*kvb.x + b1.y*kvb.y + b1.z*kvb.z + b1.w*kvb.w;
#pragma unroll
        for (int off = 32; off > 0; off >>= 1) {
            pd0 += __shfl_xor(pd0, off);
            pd1 += __shfl_xor(pd1, off);
        }

        const float f0 = (float)l0, f1 = (float)l1;
        float lv0 = (f0 < startf) ? (startf - f0) : ((f0 <= endf) ? 0.f : (f0 - endf));
        float lv1 = (f1 < startf) ? (startf - f1) : ((f1 <= endf) ? 0.f : (f1 - endf));
        float w0 = 1.f - lv0 / mem_len_f; w0 = (f0 < mem_len_f) ? w0 : 0.f;
        float w1 = 1.f - lv1 / mem_len_f; w1 = (f1 < mem_len_f) ? w1 : 0.f;

        // p = exp(tanh(s)) via tanh(s) = (e^{2s}-1)/(e^{2s}+1); clamp keeps e^{2s} finite
        float s0 = w0 * pd0 + qb; s0 = fminf(fmaxf(s0, -15.f), 15.f);
        float s1 = w1 * pd1 + qb; s1 = fminf(fmaxf(s1, -15.f), 15.f);
        float e0 = __expf(2.f * s0);
        float e1 = __expf(2.f * s1);
        const float p0 = __expf((e0 - 1.f) / (e0 + 1.f));
        const float p1 = __expf((e1 - 1.f) / (e1 + 1.f));
        const float pw0 = p0 * w0, pw1 = p1 * w1;

        accA.x += pw0*a0.x + pw1*a1.x;  accA.y += pw0*a0.y + pw1*a1.y;
        accA.z += pw0*a0.z + pw1*a1.z;  accA.w += pw0*a0.w + pw1*a1.w;
        accB.x += pw0*b0.x + pw1*b1.x;  accB.y += pw0*b0.y + pw1*b1.y;
        accB.z += pw0*b0.z + pw1*b1.z;  accB.w += pw0*b0.w + pw1*b1.w;
        vsA.x += a0.x + a1.x;  vsA.y += a0.y + a1.y;
        vsA.z += a0.z + a1.z;  vsA.w += a0.w + a1.w;
        vsB.x += b0.x + b1.x;  vsB.y += b0.y + b1.y;
        vsB.z += b0.z + b1.z;  vsB.w += b0.w + b1.w;
        denom += p0 + p1;
    }

    *(float4*)&accW[wv * 300 + 4 * lane] = accA;
    *(float4*)&vsW [wv * 300 + 4 * lane] = vsA;
    if (hasB) {
        *(float4*)&accW[wv * 300 + 256 + 4 * lane] = accB;
        *(float4*)&vsW [wv * 300 + 256 + 4 * lane] = vsB;
    }
    if (lane == 0) denomW[wv] = denom;
    __syncthreads();

    // Phase C: combine into A (= mw) and VS (= v_s), all in LDS.
    if (t < 300) {
        float ds = 0.f;
#pragma unroll
        for (int w = 0; w < 16; ++w) ds += denomW[w];
        float ms = 0.f, vs = 0.f;
#pragma unroll
        for (int w = 0; w < 16; ++w) { ms += accW[w * 300 + t]; vs += vsW[w * 300 + t]; }
        A[t] = ms / ds;
        VS[t] = vs / mem_len_f;
    }
    __syncthreads();

    // Phase D: tail. 3-way K-split over threads 0..959; 960..1023 idle but
    // participate in barriers.
    const int seg = t / 320;
    const int j = t - seg * 320;
    const bool act = (seg < 3) && (j < 300);

    // GEMM1: T = A @ Wk + bk
    if (act) {
        const int k0 = seg * 100;
        float acc = 0.f;
#pragma unroll 10
        for (int i = 0; i < 100; ++i) acc += A[k0 + i] * Wk[(k0 + i) * 300 + j];
        part[seg * 300 + j] = acc;
    }
    __syncthreads();
    if (t < 300) T[t] = part[t] + part[300 + t] + part[600 + t] + bk[t];
    __syncthreads();

    // GEMM2: A = T @ Wproj + bproj + v_s
    if (act) {
        const int k0 = seg * 100;
        float acc = 0.f;
#pragma unroll 10
        for (int i = 0; i < 100; ++i) acc += T[k0 + i] * Wproj[(k0 + i) * 300 + j];
        part[seg * 300 + j] = acc;
    }
    __syncthreads();
    if (t < 300) A[t] = part[t] + part[300 + t] + part[600 + t] + bproj[t] + VS[t];
    __syncthreads();

    // GEMM3: vms = tanh(A @ Wm + bm)
    if (act) {
        const int k0 = seg * 100;
        float acc = 0.f;
#pragma unroll 10
        for (int i = 0; i < 100; ++i) acc += A[k0 + i] * Wm[(k0 + i) * 300 + j];
        part[seg * 300 + j] = acc;
    }
    __syncthreads();
    if (t < 300) vms[t] = tanhf(part[t] + part[300 + t] + part[600 + t] + bm[t]);
    __syncthreads();

    // logits: waves 0..2 each handle one class
    if (wv < 3) {
        float p = 0.f;
#pragma unroll
        for (int k = 0; k < 5; ++k) { int d = lane + 64 * k; if (d < 300) p += vms[d] * Wd[d * 3 + wv]; }
        p = wred(p);
        if (lane == 0) lg[wv] = p + bd[wv];
    }
    __syncthreads();
    if (t == 0) {
        float l0 = lg[0], l1 = lg[1], l2 = lg[2];
        float mx = fmaxf(l0, fmaxf(l1, l2));
        float e0 = expf(l0 - mx), e1 = expf(l1 - mx), e2 = expf(l2 - mx);
        float s = e0 + e1 + e2;
        out[b * 3 + 0] = e0 / s;
        out[b * 3 + 1] = e1 / s;
        out[b * 3 + 2] = e2 / s;
    }
}

extern "C" void kernel_launch(void* const* d_in, const int* in_sizes, int n_in,
                              void* d_out, int out_size, void* d_ws, size_t ws_size,
                              hipStream_t stream)
{
    (void)in_sizes; (void)n_in; (void)out_size; (void)ws_size;
    const int*   text   = (const int*)d_in[0];
    const int*   aspect = (const int*)d_in[1];
    const int*   left   = (const int*)d_in[2];
    const float* embed  = (const float*)d_in[3];
    const float* Wx     = (const float*)d_in[4];
    // d_in[5] = Ws : dead code in reference
    const float* Wk     = (const float*)d_in[6];
    const float* bk     = (const float*)d_in[7];
    const float* Wq     = (const float*)d_in[8];
    const float* bq     = (const float*)d_in[9];
    const float* wmlp   = (const float*)d_in[10];
    const float* Wproj  = (const float*)d_in[11];
    const float* bproj  = (const float*)d_in[12];
    const float* Wm     = (const float*)d_in[13];
    const float* bm     = (const float*)d_in[14];
    const float* Wd     = (const float*)d_in[15];
    const float* bd     = (const float*)d_in[16];
    float* out = (float*)d_out;
    float* ws  = (float*)d_ws;

    hipLaunchKernelGGL(k_prep,  dim3(302), dim3(64),   0, stream, Wk, bk, Wq, bq, Wx, wmlp, ws);
    hipLaunchKernelGGL(k_hops3, dim3(1),   dim3(1024), 0, stream, Wx, ws);
    hipLaunchKernelGGL(k_fused, dim3(256), dim3(1024), 0, stream,
                       text, aspect, left, embed,
                       Wk, bk, Wproj, bproj, Wm, bm, Wd, bd, out, ws);
}